// Round 15
// baseline (263.882 us; speedup 1.0000x reference)
//
#include <hip/hip_runtime.h>
#include <hip/hip_bf16.h>

#define C_  19
#define D_  512
#define H_  4
#define DH_ 128
#define NROW 65536
#define CHP_ 96

typedef float f32x4 __attribute__((ext_vector_type(4)));
typedef short bf16x8 __attribute__((ext_vector_type(8)));

__device__ __forceinline__ unsigned short f2bf(float f) {
  union { __hip_bfloat16 h; unsigned short s; } u;
  u.h = __float2bfloat16(f);
  return u.s;
}
__device__ __forceinline__ float bf2f(unsigned short h) {
  return __uint_as_float(((unsigned int)h) << 16);
}
__device__ __forceinline__ bf16x8 ld_cvt8(const float* p) {
  f32x4 v0 = *(const f32x4*)p;
  f32x4 v1 = *(const f32x4*)(p + 4);
  bf16x8 a;
  a[0]=(short)f2bf(v0[0]); a[1]=(short)f2bf(v0[1]);
  a[2]=(short)f2bf(v0[2]); a[3]=(short)f2bf(v0[3]);
  a[4]=(short)f2bf(v1[0]); a[5]=(short)f2bf(v1[1]);
  a[6]=(short)f2bf(v1[2]); a[7]=(short)f2bf(v1[3]);
  return a;
}

// ---- prep (r13-verbatim): K/V in-block, Mtf/Utf frag-order, bo at p=80 ----
__global__ __launch_bounds__(512) void prep(
    const float* __restrict__ ce,
    const float* __restrict__ Wq, const float* __restrict__ bq,
    const float* __restrict__ Wk, const float* __restrict__ bk,
    const float* __restrict__ Wv, const float* __restrict__ bv,
    const float* __restrict__ Wo, const float* __restrict__ bo,
    unsigned short* __restrict__ Mtf, unsigned short* __restrict__ Utf,
    float* __restrict__ s0g)
{
  __shared__ float KV[2][DH_];
  __shared__ float KVp[512];

  const int p = blockIdx.x;   // 0..95
  const int m = threadIdx.x;  // 0..511
  const int mt_off = (p>>4)*8192 + (m>>5)*512 + ((((m>>3)&3)<<4) + (p&15))*8 + (m&7);
  const int ut_off = ((m>>4)*3 + (p>>5))*512 + ((((p>>3)&3)<<4) + (m&15))*8 + (p&7);
  const int c = p >> 2, h = p & 3;

  if (c >= C_) {   // dead slots; p==80 carries bo (Wa col 80 is 1.0)
    if (p < 80) { Mtf[mt_off] = 0; if (m == 0) s0g[p] = 0.f; }
    Utf[ut_off] = (p == 80) ? f2bf(bo[m]) : (unsigned short)0;
    return;
  }

  {
    const int which = m >> 8;            // 0:K 1:V
    const int dh    = (m >> 1) & 127;
    const int half  = m & 1;
    const float* w = (which ? Wv : Wk) + (size_t)(h*DH_ + dh)*D_ + half*256;
    const float* e = ce + (size_t)c*D_ + half*256;
    float acc = 0.f;
    #pragma unroll 8
    for (int d = 0; d < 256; ++d) acc = fmaf(e[d], w[d], acc);
    KVp[m] = acc;
  }
  __syncthreads();
  if (m < 256) {
    const int which = m >> 7, dh = m & 127;
    KV[which][dh] = KVp[2*m] + KVp[2*m+1] + (which ? bv : bk)[h*DH_ + dh];
  }
  __syncthreads();

  const float rs128 = 0.08838834764831843f;  // 1/sqrt(128)
  float macc = 0.f;
  #pragma unroll 4
  for (int dh = 0; dh < DH_; ++dh)
    macc = fmaf(Wq[(size_t)(h*DH_+dh)*D_ + m], KV[0][dh], macc);
  Mtf[mt_off] = f2bf(macc * rs128);

  float uacc = 0.f;
  const float* wor = Wo + (size_t)m*D_ + h*DH_;
  #pragma unroll 4
  for (int dh = 0; dh < DH_; ++dh)
    uacc = fmaf(wor[dh], KV[1][dh], uacc);
  Utf[ut_off] = f2bf(uacc);

  if (m == 0) {
    float sa = 0.f;
    for (int dh = 0; dh < DH_; ++dh) sa = fmaf(bq[h*DH_+dh], KV[0][dh], sa);
    s0g[p] = sa * rs128;
  }
}

// ---- fused16s: 1 wave / 16 rows, ZERO barriers, SLIM (3.3KB LDS, 128 VGPR) -
// No x staging: phase-1 A-frags cvt'd from global; residual re-read (L3-hot).
// 512 cols in two 256-col passes: pass A compressed to bf16 (32 VGPR),
// pass B f32; LN stats accumulated across both, wave-local shfl reduce.
__global__ __launch_bounds__(64, 4) void fused16s(
    const float* __restrict__ x,
    const unsigned short* __restrict__ Mtf,  // frag-ordered [5][16][64][8]
    const unsigned short* __restrict__ Utf,  // frag-ordered [32][3][64][8]
    const float* __restrict__ s0g,           // [80] permuted
    const float* __restrict__ gamma, const float* __restrict__ beta,
    float* __restrict__ out)
{
  __shared__ __attribute__((aligned(16))) unsigned short WaL[16][104];

  const int lane = threadIdx.x;      // 0..63
  const int lhi  = lane >> 4;
  const int llo  = lane & 15;
  const int row0 = blockIdx.x * 16;

  // ---- phase 1: S-GEMM (K=512), A from global (cvt), B = Mtf x5 ----
  {
    f32x4 acc0 = (f32x4){0,0,0,0}, acc1 = acc0, acc2 = acc0, acc3 = acc0, acc4 = acc0;
    const float* xr = x + (size_t)(row0 + llo)*D_ + lhi*8;
    #pragma unroll
    for (int ks = 0; ks < 16; ++ks) {
      bf16x8 a = ld_cvt8(xr + ks*32);
      acc0 = __builtin_amdgcn_mfma_f32_16x16x32_bf16(a, *(const bf16x8*)(Mtf + 0*8192 + ks*512 + lane*8), acc0, 0, 0, 0);
      acc1 = __builtin_amdgcn_mfma_f32_16x16x32_bf16(a, *(const bf16x8*)(Mtf + 1*8192 + ks*512 + lane*8), acc1, 0, 0, 0);
      acc2 = __builtin_amdgcn_mfma_f32_16x16x32_bf16(a, *(const bf16x8*)(Mtf + 2*8192 + ks*512 + lane*8), acc2, 0, 0, 0);
      acc3 = __builtin_amdgcn_mfma_f32_16x16x32_bf16(a, *(const bf16x8*)(Mtf + 3*8192 + ks*512 + lane*8), acc3, 0, 0, 0);
      acc4 = __builtin_amdgcn_mfma_f32_16x16x32_bf16(a, *(const bf16x8*)(Mtf + 4*8192 + ks*512 + lane*8), acc4, 0, 0, 0);
    }
    // in-register softmax over p (h = llo&3 lane-invariant under xor 4,8)
    const bool dead = (llo >= 12);   // slot p=64+llo: c = 16+(llo>>2) == 19
    float s0v0 = s0g[llo], s0v1 = s0g[16+llo], s0v2 = s0g[32+llo],
          s0v3 = s0g[48+llo], s0v4 = s0g[64+llo];
    #pragma unroll
    for (int r = 0; r < 4; ++r) {
      float v0 = acc0[r] + s0v0;
      float v1 = acc1[r] + s0v1;
      float v2 = acc2[r] + s0v2;
      float v3 = acc3[r] + s0v3;
      float v4 = dead ? -1e30f : (acc4[r] + s0v4);
      float mx = fmaxf(fmaxf(fmaxf(v0, v1), fmaxf(v2, v3)), v4);
      mx = fmaxf(mx, __shfl_xor(mx, 4, 64));
      mx = fmaxf(mx, __shfl_xor(mx, 8, 64));
      float e0 = __expf(v0 - mx), e1 = __expf(v1 - mx), e2 = __expf(v2 - mx),
            e3 = __expf(v3 - mx), e4 = dead ? 0.f : __expf(v4 - mx);
      float sm = e0 + e1 + e2 + e3 + e4;
      sm += __shfl_xor(sm, 4, 64);
      sm += __shfl_xor(sm, 8, 64);
      float inv = 1.f / sm;
      int lr = lhi*4 + r;
      WaL[lr][     llo] = f2bf(e0 * inv);
      WaL[lr][16 + llo] = f2bf(e1 * inv);
      WaL[lr][32 + llo] = f2bf(e2 * inv);
      WaL[lr][48 + llo] = f2bf(e3 * inv);
      WaL[lr][64 + llo] = f2bf(e4 * inv);
    }
    // pad cols 80..95: col 80 = 1.0 (bo slot), rest 0
    {
      int prow = lhi*4 + (llo & 3);
      int cj   = llo >> 2;
      WaL[prow][80 + cj*4 + 0] = (cj == 0) ? (unsigned short)0x3F80 : (unsigned short)0;
      WaL[prow][80 + cj*4 + 1] = 0;
      WaL[prow][80 + cj*4 + 2] = 0;
      WaL[prow][80 + cj*4 + 3] = 0;
    }
  }
  asm volatile("s_waitcnt lgkmcnt(0)" ::: "memory");
  __builtin_amdgcn_sched_barrier(0);

  float s[4] = {0,0,0,0}, q[4] = {0,0,0,0};
  unsigned int pk[32];
  f32x4 oa[16];

  // ---- pass A: cols 0..255 -> bf16-compressed ----
  #pragma unroll
  for (int i = 0; i < 16; ++i) oa[i] = (f32x4){0,0,0,0};
  #pragma unroll
  for (int ks = 0; ks < 3; ++ks) {
    bf16x8 aw = *(const bf16x8*)&WaL[llo][ks*32 + lhi*8];
    #pragma unroll
    for (int tl = 0; tl < 16; ++tl) {
      bf16x8 b = *(const bf16x8*)(Utf + (size_t)(tl*3 + ks)*512 + lane*8);
      oa[tl] = __builtin_amdgcn_mfma_f32_16x16x32_bf16(aw, b, oa[tl], 0, 0, 0);
    }
  }
  #pragma unroll
  for (int tl = 0; tl < 16; ++tl) {
    int n = tl*16 + llo;
    #pragma unroll
    for (int r = 0; r < 4; ++r) {
      float val = oa[tl][r] + x[(size_t)(row0 + lhi*4 + r)*D_ + n];
      oa[tl][r] = val;
      s[r] += val;
      q[r] = fmaf(val, val, q[r]);
    }
    pk[tl*2    ] = (unsigned int)f2bf(oa[tl][0]) | ((unsigned int)f2bf(oa[tl][1]) << 16);
    pk[tl*2 + 1] = (unsigned int)f2bf(oa[tl][2]) | ((unsigned int)f2bf(oa[tl][3]) << 16);
  }

  // ---- pass B: cols 256..511 (f32, reuse oa) ----
  #pragma unroll
  for (int i = 0; i < 16; ++i) oa[i] = (f32x4){0,0,0,0};
  #pragma unroll
  for (int ks = 0; ks < 3; ++ks) {
    bf16x8 aw = *(const bf16x8*)&WaL[llo][ks*32 + lhi*8];
    #pragma unroll
    for (int tl = 0; tl < 16; ++tl) {
      bf16x8 b = *(const bf16x8*)(Utf + (size_t)((16 + tl)*3 + ks)*512 + lane*8);
      oa[tl] = __builtin_amdgcn_mfma_f32_16x16x32_bf16(aw, b, oa[tl], 0, 0, 0);
    }
  }
  #pragma unroll
  for (int tl = 0; tl < 16; ++tl) {
    int n = 256 + tl*16 + llo;
    #pragma unroll
    for (int r = 0; r < 4; ++r) {
      float val = oa[tl][r] + x[(size_t)(row0 + lhi*4 + r)*D_ + n];
      oa[tl][r] = val;
      s[r] += val;
      q[r] = fmaf(val, val, q[r]);
    }
  }

  // ---- LN stats: reduce across the 16 llo lanes (same lhi) ----
  float mu_r[4], rstd_r[4];
  #pragma unroll
  for (int r = 0; r < 4; ++r) {
    #pragma unroll
    for (int off = 1; off < 16; off <<= 1) {
      s[r] += __shfl_xor(s[r], off, 64);
      q[r] += __shfl_xor(q[r], off, 64);
    }
    float mu  = s[r] * (1.f/(float)D_);
    float var = q[r] * (1.f/(float)D_) - mu*mu;
    mu_r[r]   = mu;
    rstd_r[r] = rsqrtf(var + 1e-5f);
  }

  // ---- store pass B (f32 regs) ----
  #pragma unroll
  for (int tl = 0; tl < 16; ++tl) {
    int n = 256 + tl*16 + llo;
    float g = gamma[n], bt = beta[n];
    #pragma unroll
    for (int r = 0; r < 4; ++r)
      out[(size_t)(row0 + lhi*4 + r)*D_ + n] = (oa[tl][r] - mu_r[r]) * rstd_r[r] * g + bt;
  }
  // ---- store pass A (unpack bf16) ----
  #pragma unroll
  for (int tl = 0; tl < 16; ++tl) {
    int n = tl*16 + llo;
    float g = gamma[n], bt = beta[n];
    float v0 = bf2f((unsigned short)(pk[tl*2    ] & 0xFFFF));
    float v1 = bf2f((unsigned short)(pk[tl*2    ] >> 16));
    float v2 = bf2f((unsigned short)(pk[tl*2 + 1] & 0xFFFF));
    float v3 = bf2f((unsigned short)(pk[tl*2 + 1] >> 16));
    const size_t ro = (size_t)(row0 + lhi*4)*D_ + n;
    out[ro        ] = (v0 - mu_r[0]) * rstd_r[0] * g + bt;
    out[ro +   D_ ] = (v1 - mu_r[1]) * rstd_r[1] * g + bt;
    out[ro + 2*D_ ] = (v2 - mu_r[2]) * rstd_r[2] * g + bt;
    out[ro + 3*D_ ] = (v3 - mu_r[3]) * rstd_r[3] * g + bt;
  }
}

extern "C" void kernel_launch(void* const* d_in, const int* in_sizes, int n_in,
                              void* d_out, int out_size, void* d_ws, size_t ws_size,
                              hipStream_t stream) {
  const float* x     = (const float*)d_in[0];
  const float* ce    = (const float*)d_in[1];
  const float* Wq    = (const float*)d_in[2];
  const float* bq    = (const float*)d_in[3];
  const float* Wk    = (const float*)d_in[4];
  const float* bk    = (const float*)d_in[5];
  const float* Wv    = (const float*)d_in[6];
  const float* bv    = (const float*)d_in[7];
  const float* Wo    = (const float*)d_in[8];
  const float* bo    = (const float*)d_in[9];
  const float* gamma = (const float*)d_in[10];
  const float* beta  = (const float*)d_in[11];
  float* out = (float*)d_out;

  char* ws = (char*)d_ws;
  unsigned short* Mtf = (unsigned short*)(ws);           // 80*512*2 = 81920
  unsigned short* Utf = (unsigned short*)(ws + 81920);   // 512*96*2 = 98304
  float* s0g          = (float*)(ws + 180224);           // 320

  prep<<<CHP_, 512, 0, stream>>>(ce, Wq, bq, Wk, bk, Wv, bv, Wo, bo,
                                 Mtf, Utf, s0g);
  fused16s<<<NROW/16, 64, 0, stream>>>(x, Mtf, Utf, s0g, gamma, beta, out);
}